// Round 11
// baseline (783.687 us; speedup 1.0000x reference)
//
#include <hip/hip_runtime.h>
#include <hip/hip_bf16.h>

#define BATCH 16
#define CH 256
#define HH 128
#define WW 128
#define HWSZ (HH * WW)
#define NHEAD 8
#define DHEAD 32
#define PW 132       // padded spatial width  (2 halo each side)
#define PPIX (132 * 132)
#define ROWS 264     // LDS row stride in shorts (132 words; XOR chunk swizzle fixes mod-32 aliasing)

typedef __attribute__((ext_vector_type(8))) short bf16x8;
typedef __attribute__((ext_vector_type(4))) float f32x4;
typedef _Float16 h2v __attribute__((ext_vector_type(2)));

__device__ __forceinline__ unsigned short f2h(float f) {
    _Float16 h = (_Float16)f;
    return __builtin_bit_cast(unsigned short, h);
}
// packed f32x2 -> bf16x2 in one u32 (v_cvt_pk_bf16_f32 on gfx950)
__device__ __forceinline__ unsigned pkbf(float a, float b) {
    __hip_bfloat162_raw r = __hip_bfloat162_raw(__float22bfloat162_rn(make_float2(a, b)));
    return (unsigned)r.x | ((unsigned)r.y << 16);
}

#if __has_builtin(__builtin_amdgcn_fdot2)
#define DOT2(a, b, c) __builtin_amdgcn_fdot2((a), (b), (c), false)
#else
#define DOT2(a, b, c) ((c) + (float)(a)[0] * (float)(b)[0] + (float)(a)[1] * (float)(b)[1])
#endif

// ---------------------------------------------------------------------------
// Kernel Z: zero the spatial border of padded K/V buffers (1040 px per b,h).
// ---------------------------------------------------------------------------
__global__ __launch_bounds__(256)
void zpad_kernel(unsigned short* __restrict__ kpad, unsigned short* __restrict__ vpad)
{
    int bid = blockIdx.x;  // 0..255 : (bh, tensor)
    unsigned short* dst = ((bid & 1) ? vpad : kpad) + (size_t)(bid >> 1) * PPIX * DHEAD;
    const uint4 z = {0u, 0u, 0u, 0u};
    for (int i = threadIdx.x; i < 1040; i += 256) {
        int row, col;
        if (i < 264)      { row = i / 132; col = i - row * 132; }
        else if (i < 528) { int j = i - 264; int r = j / 132; row = 130 + r; col = j - r * 132; }
        else              { int j = i - 528; row = 2 + (j >> 2); int c = j & 3; col = (c < 2) ? c : (128 + c); }
        uint4* p = reinterpret_cast<uint4*>(dst + (size_t)(row * PW + col) * DHEAD);
        p[0] = z; p[1] = z; p[2] = z; p[3] = z;
    }
}

// ---------------------------------------------------------------------------
// Kernel 0: convert wq|wk|wv|wfc fp32 -> bf16, stashed in d_ws tail.
// ---------------------------------------------------------------------------
__global__ __launch_bounds__(256)
void prep_kernel(const float* __restrict__ wq, const float* __restrict__ wk,
                 const float* __restrict__ wv, const float* __restrict__ wfc,
                 unsigned short* __restrict__ wb)
{
    const float* src = (blockIdx.y == 0) ? wq : (blockIdx.y == 1) ? wk
                     : (blockIdx.y == 2) ? wv : wfc;
    unsigned short* dst = wb + blockIdx.y * 65536;
    int e = (blockIdx.x * 256 + threadIdx.x) * 8;
    const float4* s = reinterpret_cast<const float4*>(src + e);
    float4 a = s[0], c = s[1];
    uint4 u;
    u.x = pkbf(a.x, a.y); u.y = pkbf(a.z, a.w);
    u.z = pkbf(c.x, c.y); u.w = pkbf(c.z, c.w);
    *reinterpret_cast<uint4*>(dst + e) = u;
}

// ---------------------------------------------------------------------------
// Kernel 1: projections -> f16, pixel-major. BM=256, BN=64, 512 threads
// (8 waves x 32 out-ch). Loads-first staging (32 strided loads in flight,
// sched_barrier-pinned), XOR chunk swizzle on LDS, single barrier.
// ---------------------------------------------------------------------------
__global__ __launch_bounds__(512)
void proj_kernel(const float* __restrict__ q, const float* __restrict__ k,
                 const float* __restrict__ v, const unsigned short* __restrict__ wb,
                 unsigned short* __restrict__ qh, unsigned short* __restrict__ kpad,
                 unsigned short* __restrict__ vpad)
{
    __shared__ __align__(16) unsigned short lB[64 * ROWS];  // 33 KB

    const int t = threadIdx.x;
    const int b = blockIdx.y;
    const int p0 = blockIdx.x * 64;
    const int z = blockIdx.z;

    const float* X; unsigned short* Y;
    if (z == 0)      { X = q; Y = qh; }
    else if (z == 1) { X = k; Y = kpad; }
    else             { X = v; Y = vpad; }
    const unsigned short* Wb = wb + z * 65536;
    X += (size_t)b * CH * HWSZ;
    const size_t pixstride = (z == 0) ? (size_t)HWSZ : (size_t)PPIX;
    Y += (size_t)b * NHEAD * pixstride * DHEAD;

    const int lane = t & 63;
    const int wid  = t >> 6;   // 0..7 : 32-channel output slab
    const int lrow = lane & 15;
    const int lkg  = lane >> 4;
    const int pB   = t & 63;   // staging pixel
    const int cg   = t >> 6;   // staging 32-channel group
    const int psw  = pB >> 3;  // swizzle key

    // ---- stage: ALL 32 strided loads first (one latency exposure) ----
    float fv[32];
    {
        const float* xb = X + p0 + pB + (size_t)(cg * 32) * HWSZ;
#pragma unroll
        for (int i = 0; i < 32; ++i) fv[i] = xb[(size_t)i * HWSZ];
    }
    __builtin_amdgcn_sched_barrier(0);
#pragma unroll
    for (int i = 0; i < 4; ++i) {
        uint4 u;
        u.x = pkbf(fv[i*8+0], fv[i*8+1]); u.y = pkbf(fv[i*8+2], fv[i*8+3]);
        u.z = pkbf(fv[i*8+4], fv[i*8+5]); u.w = pkbf(fv[i*8+6], fv[i*8+7]);
        *reinterpret_cast<uint4*>(&lB[pB * ROWS + ((cg * 4 + i) ^ psw) * 8]) = u;
    }

    // A prologue prefetch (ks=0)
    bf16x8 afc[2], afn[2];
#pragma unroll
    for (int m = 0; m < 2; ++m)
        afc[m] = *reinterpret_cast<const bf16x8*>(Wb + (wid * 32 + m * 16 + lrow) * 256 + lkg * 8);

    f32x4 acc[2][4];
    const f32x4 zero = {0.f, 0.f, 0.f, 0.f};
#pragma unroll
    for (int m = 0; m < 2; ++m)
#pragma unroll
        for (int n = 0; n < 4; ++n) acc[m][n] = zero;

    __syncthreads();   // the ONLY barrier

#pragma unroll
    for (int ks = 0; ks < 8; ++ks) {
        if (ks < 7) {
#pragma unroll
            for (int m = 0; m < 2; ++m)
                afn[m] = *reinterpret_cast<const bf16x8*>(Wb + (wid * 32 + m * 16 + lrow) * 256 + (ks + 1) * 32 + lkg * 8);
        }
        bf16x8 bfv[4];
#pragma unroll
        for (int n = 0; n < 4; ++n) {
            int row = n * 16 + lrow;
            bfv[n] = *reinterpret_cast<const bf16x8*>(&lB[row * ROWS + ((ks * 4 + lkg) ^ (row >> 3)) * 8]);
        }
#pragma unroll
        for (int m = 0; m < 2; ++m)
#pragma unroll
            for (int n = 0; n < 4; ++n)
                acc[m][n] = __builtin_amdgcn_mfma_f32_16x16x32_bf16(afc[m], bfv[n], acc[m][n], 0, 0, 0);
#pragma unroll
        for (int m = 0; m < 2; ++m) afc[m] = afn[m];
    }

    const int lr = lane >> 4, lc = lane & 15;
#pragma unroll
    for (int m = 0; m < 2; ++m)
#pragma unroll
        for (int n = 0; n < 4; ++n) {
            int d0 = m * 16 + lr * 4;            // head = wid, channel-in-head
            int p = p0 + n * 16 + lc;
            ushort4 pk;
            pk.x = f2h(acc[m][n][0]); pk.y = f2h(acc[m][n][1]);
            pk.z = f2h(acc[m][n][2]); pk.w = f2h(acc[m][n][3]);
            size_t pix;
            if (z == 0) pix = (size_t)wid * HWSZ + p;
            else { int row = p >> 7, col = p & 127; pix = (size_t)wid * PPIX + (size_t)(row + 2) * PW + (col + 2); }
            *reinterpret_cast<ushort4*>(&Y[pix * DHEAD + d0]) = pk;
        }
}

// ---------------------------------------------------------------------------
// Kernel 2: local 5x5 attention — 4 lanes per pixel, contiguous 1KB/wave.
// Output converted to BF16 (pixel-major, in place over qh).
// ---------------------------------------------------------------------------
__global__ __launch_bounds__(1024)
void attn_kernel(unsigned short* __restrict__ qh,
                 const unsigned short* __restrict__ kpad,
                 const unsigned short* __restrict__ vpad)
{
    const int t = threadIdx.x;
    const int swz = (blockIdx.x & 7) * 1024 + (blockIdx.x >> 3);
    const int bh = swz >> 6;
    const int tile = swz & 63;
    const int x0 = (tile & 7) * 16, y0 = (tile >> 3) * 16;
    const int qc = t & 3;
    const int px = (t >> 2) & 15;
    const int py = t >> 6;
    const int gx = x0 + px, gy = y0 + py;

    unsigned short* qp = qh + ((size_t)bh * HWSZ + gy * WW + gx) * DHEAD + qc * 8;
    const unsigned short* kb = kpad + (size_t)bh * PPIX * DHEAD + qc * 8;
    const unsigned short* vb = vpad + (size_t)bh * PPIX * DHEAD + qc * 8;

    union { uint4 u; h2v h2[4]; } Q;
    Q.u = *reinterpret_cast<const uint4*>(qp);

    float ew[25];
#pragma unroll
    for (int wy = 0; wy < 5; ++wy) {
        const unsigned short* krow = kb + (size_t)((gy + wy) * PW + gx) * DHEAD;
#pragma unroll
        for (int wx = 0; wx < 5; ++wx) {
            union { uint4 u; h2v h2[4]; } K;
            K.u = *reinterpret_cast<const uint4*>(krow + wx * DHEAD);
            float s = 0.f;
#pragma unroll
            for (int j = 0; j < 4; ++j)
                s = DOT2(Q.h2[j], K.h2[j], s);
            s += __shfl_xor(s, 1);
            s += __shfl_xor(s, 2);
            ew[wy * 5 + wx] = __expf(fmaxf(s, 0.f) * 0.17677669529663687f);
        }
    }

    float sum = 0.f;
#pragma unroll
    for (int i = 0; i < 25; ++i) sum += ew[i];
    const float inv = 1.f / sum;

    union { uint4 u; h2v h2[4]; } A;
    const h2v hz = {(_Float16)0.f, (_Float16)0.f};
#pragma unroll
    for (int j = 0; j < 4; ++j) A.h2[j] = hz;

#pragma unroll
    for (int wy = 0; wy < 5; ++wy) {
        const unsigned short* vrow = vb + (size_t)((gy + wy) * PW + gx) * DHEAD;
#pragma unroll
        for (int wx = 0; wx < 5; ++wx) {
            _Float16 wh = (_Float16)(ew[wy * 5 + wx] * inv);
            h2v w2 = {wh, wh};
            union { uint4 u; h2v h2[4]; } V;
            V.u = *reinterpret_cast<const uint4*>(vrow + wx * DHEAD);
#pragma unroll
            for (int j = 0; j < 4; ++j)
                A.h2[j] += w2 * V.h2[j];
        }
    }

    // f16 acc -> bf16 out (fcln consumes bf16 directly)
    uint4 o;
    o.x = pkbf((float)A.h2[0][0], (float)A.h2[0][1]);
    o.y = pkbf((float)A.h2[1][0], (float)A.h2[1][1]);
    o.z = pkbf((float)A.h2[2][0], (float)A.h2[2][1]);
    o.w = pkbf((float)A.h2[3][0], (float)A.h2[3][1]);
    *reinterpret_cast<uint4*>(qp) = o;
}

// ---------------------------------------------------------------------------
// Kernel 3: o = wfc @ attn_out + residual, LayerNorm. 512 threads, 8 waves
// x 32 out-ch. Pure uint4 B-stage (loads-first), XOR chunk swizzle.
// ---------------------------------------------------------------------------
__global__ __launch_bounds__(512)
void fcln_kernel(const unsigned short* __restrict__ ob, const unsigned short* __restrict__ wfcb,
                 const float* __restrict__ qres, const float* __restrict__ lnw,
                 const float* __restrict__ lnb, float* __restrict__ out)
{
    __shared__ __align__(16) unsigned short lB[64 * ROWS];  // 33 KB
    __shared__ float lsum[8][64];
    __shared__ float lssq[8][64];

    const int t = threadIdx.x;
    const int b = blockIdx.y;
    const int p0 = blockIdx.x * 64;

    const int lane = t & 63;
    const int wid  = t >> 6;   // 0..7
    const int lrow = lane & 15;
    const int lkg  = lane >> 4;

    // ---- stage ALL of B: 4 x uint4 per thread, loads first ----
    uint4 bv[4];
#pragma unroll
    for (int r = 0; r < 4; ++r) {
        int idx = r * 512 + t;           // 0..2047
        int h  = idx >> 8;               // head 0..7
        int rem = idx & 255;
        int px = rem >> 2, qc = rem & 3;
        bv[r] = *reinterpret_cast<const uint4*>(
            ob + ((size_t)(b * NHEAD + h) * HWSZ + p0 + px) * DHEAD + qc * 8);
    }
    __builtin_amdgcn_sched_barrier(0);
#pragma unroll
    for (int r = 0; r < 4; ++r) {
        int idx = r * 512 + t;
        int h  = idx >> 8;
        int rem = idx & 255;
        int px = rem >> 2, qc = rem & 3;
        *reinterpret_cast<uint4*>(&lB[px * ROWS + ((h * 4 + qc) ^ (px >> 3)) * 8]) = bv[r];
    }

    bf16x8 afc[2], afn[2];
#pragma unroll
    for (int m = 0; m < 2; ++m)
        afc[m] = *reinterpret_cast<const bf16x8*>(wfcb + (wid * 32 + m * 16 + lrow) * 256 + lkg * 8);

    f32x4 acc[2][4];
    const f32x4 zero = {0.f, 0.f, 0.f, 0.f};
#pragma unroll
    for (int m = 0; m < 2; ++m)
#pragma unroll
        for (int n = 0; n < 4; ++n) acc[m][n] = zero;

    __syncthreads();

#pragma unroll
    for (int ks = 0; ks < 8; ++ks) {
        if (ks < 7) {
#pragma unroll
            for (int m = 0; m < 2; ++m)
                afn[m] = *reinterpret_cast<const bf16x8*>(wfcb + (wid * 32 + m * 16 + lrow) * 256 + (ks + 1) * 32 + lkg * 8);
        }
        bf16x8 bfv[4];
#pragma unroll
        for (int n = 0; n < 4; ++n) {
            int row = n * 16 + lrow;
            bfv[n] = *reinterpret_cast<const bf16x8*>(&lB[row * ROWS + ((ks * 4 + lkg) ^ (row >> 3)) * 8]);
        }
#pragma unroll
        for (int m = 0; m < 2; ++m)
#pragma unroll
            for (int n = 0; n < 4; ++n)
                acc[m][n] = __builtin_amdgcn_mfma_f32_16x16x32_bf16(afc[m], bfv[n], acc[m][n], 0, 0, 0);
#pragma unroll
        for (int m = 0; m < 2; ++m) afc[m] = afn[m];
    }

    const int lr = lane >> 4, lc = lane & 15;
    const float* qb = qres + (size_t)b * CH * HWSZ;
#pragma unroll
    for (int m = 0; m < 2; ++m)
#pragma unroll
        for (int n = 0; n < 4; ++n)
#pragma unroll
            for (int j = 0; j < 4; ++j) {
                int o = wid * 32 + m * 16 + lr * 4 + j;
                int p = p0 + n * 16 + lc;
                acc[m][n][j] += qb[(size_t)o * HWSZ + p];
            }

    // per-pixel LN partials: this wave holds 32 channels
    float s[4], s2[4];
#pragma unroll
    for (int n = 0; n < 4; ++n) {
        float a = 0.f, c2 = 0.f;
#pragma unroll
        for (int m = 0; m < 2; ++m)
#pragma unroll
            for (int j = 0; j < 4; ++j) {
                float x = acc[m][n][j];
                a += x; c2 += x * x;
            }
        a  += __shfl_xor(a, 16);  a  += __shfl_xor(a, 32);
        c2 += __shfl_xor(c2, 16); c2 += __shfl_xor(c2, 32);
        s[n] = a; s2[n] = c2;
    }
    if (lane < 16) {
#pragma unroll
        for (int n = 0; n < 4; ++n) {
            lsum[wid][n * 16 + lane] = s[n];
            lssq[wid][n * 16 + lane] = s2[n];
        }
    }
    __syncthreads();

    float mu[4], rs[4];
#pragma unroll
    for (int n = 0; n < 4; ++n) {
        int p = n * 16 + lc;
        float ts = 0.f, tq = 0.f;
#pragma unroll
        for (int w = 0; w < 8; ++w) { ts += lsum[w][p]; tq += lssq[w][p]; }
        float m_ = ts * (1.f / 256.f);
        float v_ = tq * (1.f / 256.f) - m_ * m_;
        mu[n] = m_;
        rs[n] = rsqrtf(v_ + 1e-6f);
    }

    float* op = out + (size_t)b * CH * HWSZ;
#pragma unroll
    for (int m = 0; m < 2; ++m)
#pragma unroll
        for (int j = 0; j < 4; ++j) {
            int o = wid * 32 + m * 16 + lr * 4 + j;
            float g = lnw[o], bb = lnb[o];
#pragma unroll
            for (int n = 0; n < 4; ++n) {
                int p = p0 + n * 16 + lc;
                op[(size_t)o * HWSZ + p] = (acc[m][n][j] - mu[n]) * rs[n] * g + bb;
            }
        }
}

extern "C" void kernel_launch(void* const* d_in, const int* in_sizes, int n_in,
                              void* d_out, int out_size, void* d_ws, size_t ws_size,
                              hipStream_t stream) {
    const float* q   = (const float*)d_in[0];
    const float* k   = (const float*)d_in[1];
    const float* v   = (const float*)d_in[2];
    const float* wq  = (const float*)d_in[3];
    const float* wk  = (const float*)d_in[4];
    const float* wv  = (const float*)d_in[5];
    const float* wfc = (const float*)d_in[6];
    const float* lnw = (const float*)d_in[7];
    const float* lnb = (const float*)d_in[8];

    const size_t qsz = (size_t)BATCH * NHEAD * HWSZ * DHEAD;   // 67,108,864
    const size_t psz = (size_t)BATCH * NHEAD * PPIX * DHEAD;   // 71,368,704
    if (ws_size < (qsz + 2 * psz + 4 * 65536) * sizeof(unsigned short)) return;

    unsigned short* qh = (unsigned short*)d_ws;   // q proj (f16), then attn output (bf16, in place)
    unsigned short* kp = qh + qsz;
    unsigned short* vp = kp + psz;
    unsigned short* wb = vp + psz;                // 512KB bf16 weight stash (wq|wk|wv|wfc)

    zpad_kernel<<<256, 256, 0, stream>>>(kp, vp);
    prep_kernel<<<dim3(32, 4), 256, 0, stream>>>(wq, wk, wv, wfc, wb);
    proj_kernel<<<dim3(HWSZ / 64, BATCH, 3), 512, 0, stream>>>(q, k, v, wb, qh, kp, vp);
    attn_kernel<<<8192, 1024, 0, stream>>>(qh, kp, vp);
    fcln_kernel<<<dim3(HWSZ / 64, BATCH), 512, 0, stream>>>(qh, wb + 3 * 65536, q, lnw, lnb, (float*)d_out);
}